// Round 1
// baseline (586.875 us; speedup 1.0000x reference)
//
#include <hip/hip_runtime.h>

// CapsuleNet forward, fully fused, fp32 — wave-per-output-capsule decomposition.
//
// Block: 640 threads = 10 waves, wave o owns output capsule o, for M=4 batches.
// Lane layout within a wave: lane = ig*16 + d,  ig in [0,4), d in [0,16).
//   Lane (ig,d) owns priors P[m][k] for i = 4k+ig (k=0..8), output dim d.
// Reductions:
//   sum over i  : 9 lane-local FMAs + shfl_xor(16) + shfl_xor(32)
//   squash over d / agreement sum over d : shfl_xor(1,2,4,8) within 16 lanes
// Only cross-wave traffic: softmax denominator over o (tiny LDS + 6 barriers/block).
// Softmax state is kept as unnormalized numerators n[m][o][i] in LDS
// (n <- p_prev * exp(delta); uniform-over-o scaling cancels in softmax).

constexpr int OC = 10, NI = 36, OD = 16, IL = 8;
constexpr int M  = 4;              // batches per block
constexpr int NT = 64 * OC;        // 640 threads

__global__ __launch_bounds__(NT, 5)
void capsnet_kernel(const float* __restrict__ xg,
                    const float* __restrict__ cwg,
                    const float* __restrict__ lwg,
                    float* __restrict__ outg)
{
    __shared__ float xs[M * 9];
    __shared__ float cw[288];
    __shared__ float caps[M * NI * IL];   // [m][i][l]
    __shared__ float pl[M * OC * NI];     // softmax numerators [m][o][i]
    __shared__ float sv[M * NI];          // 1 / sum_o numerator, [m][i]

    const int t  = threadIdx.x;
    const int b0 = blockIdx.x * M;

    if (t < M * 9) xs[t] = xg[b0 * 9 + t];
    if (t < 288)   cw[t] = cwg[t];
    __syncthreads();

    // ---- conv (1->32ch, 3x3, pad 1) + squash over capsule length -> caps ----
    if (t < M * NI) {
        const int m  = t / NI;
        const int ci = t % NI;
        const int cg = ci & 3;            // capsule group (channel block of 8)
        const int wx = (ci >> 2) % 3;
        const int hx = ci / 12;
        float acc[IL] = {};
        #pragma unroll
        for (int kh = 0; kh < 3; ++kh) {
            const int xh = hx + kh - 1;
            if (xh < 0 || xh > 2) continue;
            #pragma unroll
            for (int kw = 0; kw < 3; ++kw) {
                const int xw = wx + kw - 1;
                if (xw < 0 || xw > 2) continue;
                const float xv = xs[m * 9 + xh * 3 + xw];
                #pragma unroll
                for (int l = 0; l < IL; ++l)
                    acc[l] += xv * cw[(cg * 8 + l) * 9 + kh * 3 + kw];
            }
        }
        float n2 = 0.f;
        #pragma unroll
        for (int l = 0; l < IL; ++l) n2 += acc[l] * acc[l];
        const float sc = n2 / (1.f + n2) * rsqrtf(n2 + 1e-8f);
        #pragma unroll
        for (int l = 0; l < IL; ++l) caps[t * IL + l] = acc[l] * sc;
    }
    __syncthreads();

    const int o    = t >> 6;      // wave id == output capsule
    const int lane = t & 63;
    const int ig   = lane >> 4;   // i-subgroup: i = 4k + ig
    const int d    = lane & 15;   // output dim

    // ---- priors: P[m][k] = sum_l w[o][4k+ig][d][l] * caps[m][4k+ig][l] ----
    // Wave-level global reads are fully coalesced: at step k the 64 lanes cover
    // lin_w[o][4k..4k+4)[0..16)[0..8) = one contiguous 2 KB span (L2-resident).
    float P[M][9];
    const float* wp = lwg + ((o * NI + ig) * OD + d) * IL;
    #pragma unroll 3
    for (int k = 0; k < 9; ++k) {
        const float4 wa = *reinterpret_cast<const float4*>(wp + k * (4 * OD * IL));
        const float4 wb = *reinterpret_cast<const float4*>(wp + k * (4 * OD * IL) + 4);
        const int i = 4 * k + ig;
        #pragma unroll
        for (int m = 0; m < M; ++m) {
            const float4 ca = *reinterpret_cast<const float4*>(&caps[(m * NI + i) * IL]);
            const float4 cb = *reinterpret_cast<const float4*>(&caps[(m * NI + i) * IL + 4]);
            P[m][k] = wa.x * ca.x + wa.y * ca.y + wa.z * ca.z + wa.w * ca.w
                    + wb.x * cb.x + wb.y * cb.y + wb.z * cb.z + wb.w * cb.w;
        }
    }

    float ov[M];

    // ---- routing iteration 0: p = 0.1 uniform (softmax of zero logits) ----
    #pragma unroll
    for (int m = 0; m < M; ++m) {
        float s = 0.f;
        #pragma unroll
        for (int k = 0; k < 9; ++k) s += P[m][k];
        s *= 0.1f;
        s += __shfl_xor(s, 16);
        s += __shfl_xor(s, 32);
        float n2 = s * s;
        n2 += __shfl_xor(n2, 1);
        n2 += __shfl_xor(n2, 2);
        n2 += __shfl_xor(n2, 4);
        n2 += __shfl_xor(n2, 8);
        const float sc = n2 / (1.f + n2) * rsqrtf(n2 + 1e-8f);
        ov[m] = s * sc;
    }
    // agreement -> numerator n = exp(delta)  (uniform 0.1 prior cancels in softmax)
    #pragma unroll
    for (int m = 0; m < M; ++m) {
        #pragma unroll
        for (int k = 0; k < 9; ++k) {
            float a = P[m][k] * ov[m];
            a += __shfl_xor(a, 1);
            a += __shfl_xor(a, 2);
            a += __shfl_xor(a, 4);
            a += __shfl_xor(a, 8);
            if (d == 0) pl[(m * OC + o) * NI + 4 * k + ig] = __expf(a);
        }
    }
    __syncthreads();
    if (t < M * NI) {                       // softmax denominator over o
        const int m = t / NI, i = t % NI;
        float ss = 0.f;
        #pragma unroll
        for (int oo = 0; oo < OC; ++oo) ss += pl[(m * OC + oo) * NI + i];
        sv[t] = 1.f / ss;
    }
    __syncthreads();

    // ---- routing iteration 1 ----
    #pragma unroll
    for (int m = 0; m < M; ++m) {
        float s = 0.f;
        #pragma unroll
        for (int k = 0; k < 9; ++k) {
            const int i = 4 * k + ig;
            s += pl[(m * OC + o) * NI + i] * sv[m * NI + i] * P[m][k];
        }
        s += __shfl_xor(s, 16);
        s += __shfl_xor(s, 32);
        float n2 = s * s;
        n2 += __shfl_xor(n2, 1);
        n2 += __shfl_xor(n2, 2);
        n2 += __shfl_xor(n2, 4);
        n2 += __shfl_xor(n2, 8);
        const float sc = n2 / (1.f + n2) * rsqrtf(n2 + 1e-8f);
        ov[m] = s * sc;
    }
    // agreement -> n' = (n * sv) * exp(delta)
    #pragma unroll
    for (int m = 0; m < M; ++m) {
        #pragma unroll
        for (int k = 0; k < 9; ++k) {
            float a = P[m][k] * ov[m];
            a += __shfl_xor(a, 1);
            a += __shfl_xor(a, 2);
            a += __shfl_xor(a, 4);
            a += __shfl_xor(a, 8);
            if (d == 0) {
                const int i   = 4 * k + ig;
                const int idx = (m * OC + o) * NI + i;
                pl[idx] = pl[idx] * sv[m * NI + i] * __expf(a);
            }
        }
    }
    __syncthreads();
    if (t < M * NI) {
        const int m = t / NI, i = t % NI;
        float ss = 0.f;
        #pragma unroll
        for (int oo = 0; oo < OC; ++oo) ss += pl[(m * OC + oo) * NI + i];
        sv[t] = 1.f / ss;
    }
    __syncthreads();

    // ---- routing iteration 2 (final): emit out ----
    #pragma unroll
    for (int m = 0; m < M; ++m) {
        float s = 0.f;
        #pragma unroll
        for (int k = 0; k < 9; ++k) {
            const int i = 4 * k + ig;
            s += pl[(m * OC + o) * NI + i] * sv[m * NI + i] * P[m][k];
        }
        s += __shfl_xor(s, 16);
        s += __shfl_xor(s, 32);
        float n2 = s * s;
        n2 += __shfl_xor(n2, 1);
        n2 += __shfl_xor(n2, 2);
        n2 += __shfl_xor(n2, 4);
        n2 += __shfl_xor(n2, 8);
        const float sc = n2 / (1.f + n2) * rsqrtf(n2 + 1e-8f);
        if (ig == 0) outg[(b0 + m) * (OC * OD) + o * OD + d] = s * sc;
    }
}

extern "C" void kernel_launch(void* const* d_in, const int* in_sizes, int n_in,
                              void* d_out, int out_size, void* d_ws, size_t ws_size,
                              hipStream_t stream) {
    const float* x  = (const float*)d_in[0];   // [B,1,3,3]
    const float* cwp = (const float*)d_in[1];  // [32,1,3,3]
    const float* lw = (const float*)d_in[2];   // [10,36,16,8]
    float* out = (float*)d_out;                // [B,10,16]
    const int B = in_sizes[0] / 9;             // 16384
    dim3 grid(B / M), block(NT);
    capsnet_kernel<<<grid, block, 0, stream>>>(x, cwp, lw, out);
}

// Round 2
// 379.250 us; speedup vs baseline: 1.5475x; 1.5475x over previous
//
#include <hip/hip_runtime.h>

// CapsuleNet forward, fully fused, fp32 — wave-per-output-capsule decomposition.
//
// Block: 640 threads = 10 waves, wave o owns output capsule o, for M=4 batches.
// Lane layout within a wave: lane = ig*16 + d,  ig in [0,4), d in [0,16).
//   Lane (ig,d) owns priors P[m][k] for i = 4k+ig (k=0..8), output dim d.
// Reductions:
//   sum over i  : 9 lane-local FMAs + shfl_xor(16) + shfl_xor(32)
//   squash over d / agreement sum over d : shfl_xor(1,2,4,8) within 16 lanes
// Only cross-wave traffic: softmax denominator over o (tiny LDS + 6 barriers/block).
// Softmax state is kept as unnormalized numerators n[m][o][i] in LDS
// (n <- p_prev * exp(delta); uniform-over-o scaling cancels in softmax).
//
// R1 lesson: the priors k-loop MUST be fully unrolled — "#pragma unroll 3"
// left k runtime, so P[m][k] was runtime-indexed -> scratch (377 MB of spill
// traffic, 3x slowdown). All P accesses below are compile-time-indexed.

constexpr int OC = 10, NI = 36, OD = 16, IL = 8;
constexpr int M  = 4;              // batches per block
constexpr int NT = 64 * OC;        // 640 threads

__global__ __launch_bounds__(NT, 5)
void capsnet_kernel(const float* __restrict__ xg,
                    const float* __restrict__ cwg,
                    const float* __restrict__ lwg,
                    float* __restrict__ outg)
{
    __shared__ float xs[M * 9];
    __shared__ float cw[288];
    __shared__ float caps[M * NI * IL];   // [m][i][l]
    __shared__ float pl[M * OC * NI];     // softmax numerators [m][o][i]
    __shared__ float sv[M * NI];          // 1 / sum_o numerator, [m][i]

    const int t  = threadIdx.x;
    const int b0 = blockIdx.x * M;

    if (t < M * 9) xs[t] = xg[b0 * 9 + t];
    if (t < 288)   cw[t] = cwg[t];
    __syncthreads();

    // ---- conv (1->32ch, 3x3, pad 1) + squash over capsule length -> caps ----
    if (t < M * NI) {
        const int m  = t / NI;
        const int ci = t % NI;
        const int cg = ci & 3;            // capsule group (channel block of 8)
        const int wx = (ci >> 2) % 3;
        const int hx = ci / 12;
        float acc[IL] = {};
        #pragma unroll
        for (int kh = 0; kh < 3; ++kh) {
            const int xh = hx + kh - 1;
            if (xh < 0 || xh > 2) continue;
            #pragma unroll
            for (int kw = 0; kw < 3; ++kw) {
                const int xw = wx + kw - 1;
                if (xw < 0 || xw > 2) continue;
                const float xv = xs[m * 9 + xh * 3 + xw];
                #pragma unroll
                for (int l = 0; l < IL; ++l)
                    acc[l] += xv * cw[(cg * 8 + l) * 9 + kh * 3 + kw];
            }
        }
        float n2 = 0.f;
        #pragma unroll
        for (int l = 0; l < IL; ++l) n2 += acc[l] * acc[l];
        const float sc = n2 / (1.f + n2) * rsqrtf(n2 + 1e-8f);
        #pragma unroll
        for (int l = 0; l < IL; ++l) caps[t * IL + l] = acc[l] * sc;
    }
    __syncthreads();

    const int o    = t >> 6;      // wave id == output capsule
    const int lane = t & 63;
    const int ig   = lane >> 4;   // i-subgroup: i = 4k + ig
    const int d    = lane & 15;   // output dim

    // ---- priors: P[m][k] = sum_l w[o][4k+ig][d][l] * caps[m][4k+ig][l] ----
    // Wave-level global reads are fully coalesced: at step k the 64 lanes cover
    // lin_w[o][4k..4k+4)[0..16)[0..8) = one contiguous 2 KB span (L2-resident).
    float P[M][9];
    const float* wp = lwg + ((o * NI + ig) * OD + d) * IL;
    #pragma unroll
    for (int k = 0; k < 9; ++k) {   // FULL unroll: P must stay in registers
        const float4 wa = *reinterpret_cast<const float4*>(wp + k * (4 * OD * IL));
        const float4 wb = *reinterpret_cast<const float4*>(wp + k * (4 * OD * IL) + 4);
        const int i = 4 * k + ig;
        #pragma unroll
        for (int m = 0; m < M; ++m) {
            const float4 ca = *reinterpret_cast<const float4*>(&caps[(m * NI + i) * IL]);
            const float4 cb = *reinterpret_cast<const float4*>(&caps[(m * NI + i) * IL + 4]);
            P[m][k] = wa.x * ca.x + wa.y * ca.y + wa.z * ca.z + wa.w * ca.w
                    + wb.x * cb.x + wb.y * cb.y + wb.z * cb.z + wb.w * cb.w;
        }
    }

    float ov[M];

    // ---- routing iteration 0: p = 0.1 uniform (softmax of zero logits) ----
    #pragma unroll
    for (int m = 0; m < M; ++m) {
        float s = 0.f;
        #pragma unroll
        for (int k = 0; k < 9; ++k) s += P[m][k];
        s *= 0.1f;
        s += __shfl_xor(s, 16);
        s += __shfl_xor(s, 32);
        float n2 = s * s;
        n2 += __shfl_xor(n2, 1);
        n2 += __shfl_xor(n2, 2);
        n2 += __shfl_xor(n2, 4);
        n2 += __shfl_xor(n2, 8);
        const float sc = n2 / (1.f + n2) * rsqrtf(n2 + 1e-8f);
        ov[m] = s * sc;
    }
    // agreement -> numerator n = exp(delta)  (uniform 0.1 prior cancels in softmax)
    #pragma unroll
    for (int m = 0; m < M; ++m) {
        #pragma unroll
        for (int k = 0; k < 9; ++k) {
            float a = P[m][k] * ov[m];
            a += __shfl_xor(a, 1);
            a += __shfl_xor(a, 2);
            a += __shfl_xor(a, 4);
            a += __shfl_xor(a, 8);
            if (d == 0) pl[(m * OC + o) * NI + 4 * k + ig] = __expf(a);
        }
    }
    __syncthreads();
    if (t < M * NI) {                       // softmax denominator over o
        const int m = t / NI, i = t % NI;
        float ss = 0.f;
        #pragma unroll
        for (int oo = 0; oo < OC; ++oo) ss += pl[(m * OC + oo) * NI + i];
        sv[t] = 1.f / ss;
    }
    __syncthreads();

    // ---- routing iteration 1 ----
    #pragma unroll
    for (int m = 0; m < M; ++m) {
        float s = 0.f;
        #pragma unroll
        for (int k = 0; k < 9; ++k) {
            const int i = 4 * k + ig;
            s += pl[(m * OC + o) * NI + i] * sv[m * NI + i] * P[m][k];
        }
        s += __shfl_xor(s, 16);
        s += __shfl_xor(s, 32);
        float n2 = s * s;
        n2 += __shfl_xor(n2, 1);
        n2 += __shfl_xor(n2, 2);
        n2 += __shfl_xor(n2, 4);
        n2 += __shfl_xor(n2, 8);
        const float sc = n2 / (1.f + n2) * rsqrtf(n2 + 1e-8f);
        ov[m] = s * sc;
    }
    // agreement -> n' = (n * sv) * exp(delta)
    #pragma unroll
    for (int m = 0; m < M; ++m) {
        #pragma unroll
        for (int k = 0; k < 9; ++k) {
            float a = P[m][k] * ov[m];
            a += __shfl_xor(a, 1);
            a += __shfl_xor(a, 2);
            a += __shfl_xor(a, 4);
            a += __shfl_xor(a, 8);
            if (d == 0) {
                const int i   = 4 * k + ig;
                const int idx = (m * OC + o) * NI + i;
                pl[idx] = pl[idx] * sv[m * NI + i] * __expf(a);
            }
        }
    }
    __syncthreads();
    if (t < M * NI) {
        const int m = t / NI, i = t % NI;
        float ss = 0.f;
        #pragma unroll
        for (int oo = 0; oo < OC; ++oo) ss += pl[(m * OC + oo) * NI + i];
        sv[t] = 1.f / ss;
    }
    __syncthreads();

    // ---- routing iteration 2 (final): emit out ----
    #pragma unroll
    for (int m = 0; m < M; ++m) {
        float s = 0.f;
        #pragma unroll
        for (int k = 0; k < 9; ++k) {
            const int i = 4 * k + ig;
            s += pl[(m * OC + o) * NI + i] * sv[m * NI + i] * P[m][k];
        }
        s += __shfl_xor(s, 16);
        s += __shfl_xor(s, 32);
        float n2 = s * s;
        n2 += __shfl_xor(n2, 1);
        n2 += __shfl_xor(n2, 2);
        n2 += __shfl_xor(n2, 4);
        n2 += __shfl_xor(n2, 8);
        const float sc = n2 / (1.f + n2) * rsqrtf(n2 + 1e-8f);
        if (ig == 0) outg[(b0 + m) * (OC * OD) + o * OD + d] = s * sc;
    }
}

extern "C" void kernel_launch(void* const* d_in, const int* in_sizes, int n_in,
                              void* d_out, int out_size, void* d_ws, size_t ws_size,
                              hipStream_t stream) {
    const float* x  = (const float*)d_in[0];   // [B,1,3,3]
    const float* cwp = (const float*)d_in[1];  // [32,1,3,3]
    const float* lw = (const float*)d_in[2];   // [10,36,16,8]
    float* out = (float*)d_out;                // [B,10,16]
    const int B = in_sizes[0] / 9;             // 16384
    dim3 grid(B / M), block(NT);
    capsnet_kernel<<<grid, block, 0, stream>>>(x, cwp, lw, out);
}